// Round 15
// baseline (169.935 us; speedup 1.0000x reference)
//
#include <hip/hip_runtime.h>

#define BDIM 32768
#define VDIM 256
#define KVAR 4
#define EDIM 2048
#define SEGS 16
#define SEGLEN 128   // EDIM / SEGS

typedef __attribute__((ext_vector_type(8))) short short8;
typedef __attribute__((ext_vector_type(4))) float f32x4;

__device__ __forceinline__ unsigned short f2b(float f){
  union { float f; unsigned u; } v; v.f = f;
  unsigned r = v.u + 0x7FFFu + ((v.u >> 16) & 1u);   // round-to-nearest-even
  return (unsigned short)(r >> 16);
}
__device__ __forceinline__ float b2f(unsigned short h){
  union { unsigned u; float f; } v; v.u = ((unsigned)h) << 16;
  return v.f;
}
__device__ __forceinline__ short8 ldb8(const unsigned short* p){
  return *(const short8*)p;
}

// async 16B global -> LDS (dest = wave-uniform base + lane*16)
__device__ __forceinline__ void gl_lds16(const unsigned short* g, unsigned short* l){
  __builtin_amdgcn_global_load_lds(
      (const __attribute__((address_space(1))) unsigned int*)g,
      (__attribute__((address_space(3))) unsigned int*)l, 16, 0, 0);
}

// ---- LDS staging (all source-swizzled: LDS 16B-slot s of row r holds global
// slot s ^ (r&7); reads XOR the same -> conflict-free) ----------------------
// B panel K-chunk: 256 rows x 64 k (32 KB). 8 waves x 4 issues x 1 KB.
// NOTE: exactly 4 global_load_lds per wave per unit -- the counted-vmcnt
// schedule below depends on this (vmcnt(4) = "my previous unit landed").
__device__ __forceinline__ void stage256(const unsigned short* Bt, int kB,
                                         int w, int lane, unsigned short* Bs){
#pragma unroll
  for (int i = 0; i < 4; i++){
    int g8 = i*8 + w;                  // row-group of 8 (0..31)
    int r  = g8*8 + (lane >> 3);
    int s  = lane & 7;
    gl_lds16(Bt + (size_t)r*VDIM + kB + ((s ^ (r & 7)) << 3),
             Bs + (size_t)g8*512);
  }
}
// 128-row panel K-chunk (16 KB). 8 waves x 2 issues.
__device__ __forceinline__ void stage128(const unsigned short* Bt, int kB,
                                         int w, int lane, unsigned short* Bs){
#pragma unroll
  for (int i = 0; i < 2; i++){
    int g8 = i*8 + w;                  // 0..15
    int r  = g8*8 + (lane >> 3);       // 0..127
    int s  = lane & 7;
    gl_lds16(Bt + (size_t)r*VDIM + kB + ((s ^ (r & 7)) << 3),
             Bs + (size_t)g8*512);
  }
}
// XB stripe: 64 rows x 256 cols (32 KB), full-width swizzled rows
// (same element layout as buf: elem(r,c) at r*256 + (c ^ ((r&7)<<3))).
__device__ __forceinline__ void stageA64(const unsigned short* XBg, int rowBlk,
                                         int w, int lane, unsigned short* As){
#pragma unroll
  for (int i = 0; i < 4; i++){
    int pair = i*8 + w;                // 0..31, 2 rows per 1KB issue
    int r = pair*2 + (lane >> 5);      // 0..63
    int s = lane & 31;                 // 16B slot within 512B row
    gl_lds16(XBg + (size_t)(rowBlk + r)*VDIM + ((s ^ (r & 7)) << 3),
             As + (size_t)pair*512);
  }
}

// swizzled B-fragment read (klocal = k within 64-chunk, multiple of 8)
__device__ __forceinline__ short8 bs_frag(const unsigned short* Bs, int c, int klocal){
  int slot = klocal >> 3;
  return *(const short8*)&Bs[(size_t)c*64 + ((slot ^ (c & 7)) << 3)];
}

// ---- MFMA chunk core (one 64-wide K-chunk) ---------------------------------
// D frag: col = lane&15, row = (lane>>4)*4 + reg   [measured: learn_hip m89]
// A from swizzled 256-elem LDS rows (xbs or buf); B from swizzled Bs chunk.
template<int NF>
__device__ __forceinline__ void mm_lA(const unsigned short* Alds,
                                      const unsigned short* Bs,
                                      int rl0, int c0, int kb, int kB,
                                      f32x4 (&acc)[2][NF])
{
  int sw = (rl0 & 7) << 3;             // (rl0+16)&7 == rl0&7
#pragma unroll
  for (int k = 0; k < 2; k++){
    int ka = kB + k*32 + kb;
    short8 a0 = *(const short8*)&Alds[(size_t)rl0 * 256 + (ka ^ sw)];
    short8 a1 = *(const short8*)&Alds[(size_t)(rl0+16) * 256 + (ka ^ sw)];
#pragma unroll
    for (int fn = 0; fn < NF; fn++){
      short8 b = bs_frag(Bs, c0 + fn*16, k*32 + kb);
      acc[0][fn] = __builtin_amdgcn_mfma_f32_16x16x32_bf16(a0, b, acc[0][fn], 0, 0, 0);
      acc[1][fn] = __builtin_amdgcn_mfma_f32_16x16x32_bf16(a1, b, acc[1][fn], 0, 0, 0);
    }
  }
}
// single 16-row A frag from swizzled LDS (ldaE-elem rows), B per-lane global
// (tiny W2 panel, stage-5 only)
template<int NF, int KSZ>
__device__ __forceinline__ void mm_l1(const unsigned short* Alds, int ldaE,
                                      const unsigned short* Bt, int ldb,
                                      int rl0, int c0, int kb,
                                      f32x4 (&acc)[NF])
{
  int sw = (rl0 & 7) << 3;
#pragma unroll
  for (int k0 = 0; k0 < KSZ; k0 += 32){
    int ka = k0 + kb;
    short8 a0 = *(const short8*)&Alds[(size_t)rl0 * ldaE + (ka ^ sw)];
#pragma unroll
    for (int fn = 0; fn < NF; fn++){
      short8 b = ldb8(Bt + (size_t)(c0 + fn*16)*ldb + ka);
      acc[fn] = __builtin_amdgcn_mfma_f32_16x16x32_bf16(a0, b, acc[fn], 0, 0, 0);
    }
  }
}

// ---- merged prep + seg_build (block-partitioned) ---------------------------
__global__ __launch_bounds__(256) void prep_seg(
    const float* X, const float* IV, const int* ivars,
    const float* eW1, const float* eW2, const float* pW1, const float* pW2,
    const int* cidx, const int* eidx, const float* stren,
    unsigned short* XB,
    unsigned short* bt1, unsigned short* bt2,
    unsigned short* w1ab, unsigned short* w1c,
    unsigned short* w2bf, float* w1bcol, int* colmap,
    float* delta, float* segs)
{
  if (blockIdx.x < 1024){
    __shared__ int lc[SEGLEN];
    __shared__ int le[SEGLEN];
    __shared__ float la[SEGLEN];
    int bid = blockIdx.x;            // 64 per segment, 4 rows each
    int seg = bid >> 6;
    int rowbase = (bid & 63) * 4;
    int w = threadIdx.x >> 6, lane = threadIdx.x & 63;
    int row = rowbase + w;
    int k0 = seg * SEGLEN;
    for (int t = threadIdx.x; t < SEGLEN; t += 256){
      lc[t] = cidx[k0 + t]; le[t] = eidx[k0 + t]; la[t] = stren[k0 + t] * 0.1f;
    }
    __syncthreads();
    float r0 = (row == lane)        ? 1.f : 0.f;
    float r1 = (row == lane + 64)   ? 1.f : 0.f;
    float r2 = (row == lane + 128)  ? 1.f : 0.f;
    float r3 = (row == lane + 192)  ? 1.f : 0.f;
    for (int t = 0; t < SEGLEN; t++){
      int cs = __builtin_amdgcn_readfirstlane(lc[t]);
      int es = __builtin_amdgcn_readfirstlane(le[t]);
      float a = la[t];
      float vr;
      switch (cs >> 6){ case 0: vr = r0; break; case 1: vr = r1; break;
                        case 2: vr = r2; break; default: vr = r3; }
      float v = __shfl(vr, cs & 63, 64);
      float add = (lane == (es & 63)) ? a * v : 0.f;
      switch (es >> 6){ case 0: r0 += add; break; case 1: r1 += add; break;
                        case 2: r2 += add; break; default: r3 += add; }
    }
    float* out = segs + (size_t)seg * 65536 + (size_t)row * 256;
    out[lane] = r0; out[lane + 64] = r1; out[lane + 128] = r2; out[lane + 192] = r3;
    return;
  }
  int stride = 1024 * 256;
  int g0 = (blockIdx.x - 1024) * 256 + threadIdx.x;
  for (int i = g0; i < (BDIM * VDIM) / 8; i += stride){
    const float* p = X + (size_t)i * 8;
    f32x4 lo = *(const f32x4*)p;
    f32x4 hi = *(const f32x4*)(p + 4);
    short8 r;
    r[0]=(short)f2b(lo[0]); r[1]=(short)f2b(lo[1]); r[2]=(short)f2b(lo[2]); r[3]=(short)f2b(lo[3]);
    r[4]=(short)f2b(hi[0]); r[5]=(short)f2b(hi[1]); r[6]=(short)f2b(hi[2]); r[7]=(short)f2b(hi[3]);
    *(short8*)(XB + (size_t)i * 8) = r;
  }
  for (int i = g0; i < 65536; i += stride) bt1[i] = f2b(eW1[i]);
  for (int i = g0; i < 65536; i += stride){
    int v = i >> 8, r = i & 255;
    bt2[i] = f2b(eW2[(r >> 6) * 16384 + v * 64 + (r & 63)]);
  }
  for (int i = g0; i < 32768; i += stride){
    int o = i >> 8, v = i & 255;
    w1ab[i] = f2b(pW1[o*768 + v] + pW1[o*768 + 256 + v]);
    w1c[i]  = f2b(pW1[o*768 + 512 + v]);
  }
  for (int i = g0; i < 8192; i += stride) w2bf[i] = f2b(pW2[i]);
  for (int i = g0; i < 512; i += stride){
    int o = i >> 2, k = i & 3;
    w1bcol[i] = pW1[o*768 + 256 + ivars[k]];
  }
  for (int i = g0; i < VDIM; i += stride){
    int m = -1;
#pragma unroll
    for (int k = 0; k < KVAR; k++) if (ivars[k] == i) m = k;
    colmap[i] = m;
  }
  for (int i = g0; i < BDIM * KVAR; i += stride){
    int b = i >> 2, k = i & 3;
    delta[i] = IV[i] - X[(size_t)b * VDIM + ivars[k]];
  }
}

// ---- combine: Out[m] = S[4m]*S[4m+1]*S[4m+2]*S[4m+3], 4 rows per block -----
__global__ __launch_bounds__(256) void combine4(const float* S, float* Out)
{
  int m = blockIdx.x >> 6;
  int rb = (blockIdx.x & 63) * 4;
  int c = threadIdx.x;
  __shared__ float v[4][256];
  const float* base = S + (size_t)m * 4 * 65536;
#pragma unroll
  for (int r = 0; r < 4; r++) v[r][c] = base[(size_t)(rb + r) * 256 + c];
  __syncthreads();
  for (int p = 1; p < 4; p++){
    const float* Bm = base + (size_t)p * 65536;
    float a0 = 0.f, a1 = 0.f, a2 = 0.f, a3 = 0.f;
    for (int k = 0; k < 256; k += 4){
      f32x4 v0 = *(const f32x4*)&v[0][k];
      f32x4 v1 = *(const f32x4*)&v[1][k];
      f32x4 v2 = *(const f32x4*)&v[2][k];
      f32x4 v3 = *(const f32x4*)&v[3][k];
#pragma unroll
      for (int j = 0; j < 4; j++){
        float bk = Bm[(size_t)(k + j) * 256 + c];
        a0 += v0[j] * bk; a1 += v1[j] * bk; a2 += v2[j] * bk; a3 += v3[j] * bk;
      }
    }
    __syncthreads();
    v[0][c] = a0; v[1][c] = a1; v[2][c] = a2; v[3][c] = a3;
    __syncthreads();
  }
#pragma unroll
  for (int r = 0; r < 4; r++) Out[(size_t)m * 65536 + (size_t)(rb + r) * 256 + c] = v[r][c];
}

// ---- M = R*R*R, written transposed bf16: Mt[c][r] --------------------------
__global__ __launch_bounds__(256) void powM(const float* R, unsigned short* Mt)
{
  int rb = blockIdx.x * 4;
  int c = threadIdx.x;
  __shared__ float v[4][256];
#pragma unroll
  for (int r = 0; r < 4; r++) v[r][c] = R[(size_t)(rb + r) * 256 + c];
  __syncthreads();
  for (int p = 0; p < 2; p++){
    float a0 = 0.f, a1 = 0.f, a2 = 0.f, a3 = 0.f;
    for (int k = 0; k < 256; k += 4){
      f32x4 v0 = *(const f32x4*)&v[0][k];
      f32x4 v1 = *(const f32x4*)&v[1][k];
      f32x4 v2 = *(const f32x4*)&v[2][k];
      f32x4 v3 = *(const f32x4*)&v[3][k];
#pragma unroll
      for (int j = 0; j < 4; j++){
        float bk = R[(size_t)(k + j) * 256 + c];
        a0 += v0[j] * bk; a1 += v1[j] * bk; a2 += v2[j] * bk; a3 += v3[j] * bk;
      }
    }
    __syncthreads();
    v[0][c] = a0; v[1][c] = a1; v[2][c] = a2; v[3][c] = a3;
    __syncthreads();
  }
#pragma unroll
  for (int r = 0; r < 4; r++) Mt[(size_t)c * 256 + (rb + r)] = f2b(v[r][c]);
}

// ============================================================================
// MEGA3V2: r14 kernel + COUNTED-VMCNT chunk schedule (T4, m201 2-barrier form).
// The old per-chunk __syncthreads = s_waitcnt vmcnt(0) drained the
// just-issued prefetch -> the "2-phase prefetch" never overlapped anything
// (guide m218: drain-0 pipelining == no pipelining; counted vmcnt is the
// lever, +38-73%).  New per-chunk schedule:
//   s_barrier              (all waves done reading the buffer being overwritten)
//   issue unit u+1         (4 global_load_lds per wave, exact count)
//   s_waitcnt vmcnt(4)     (chunk u's loads landed; u+1's stay IN FLIGHT
//                           across the barrier)
//   s_barrier + sched_barrier(0)   (rule #18 fence)
//   MFMA chunk u
// Stage-boundary epilogues keep __syncthreads (4 full drains vs 16).
// Deferred output stores (r14) retained.  Everything else identical to the
// r7/r12/r14-measured 83us kernel.
// ============================================================================
__global__ __launch_bounds__(512) void mega3(
    const float* IV, const unsigned short* XB,
    const unsigned short* Bt1, const unsigned short* Bt2, const unsigned short* Mt,
    const unsigned short* W1ab, const unsigned short* W1c, const unsigned short* W2bf,
    const float* eb1, const float* eb2, const float* delta, const int* colmap,
    const float* w1bcol, const float* pb1, const float* pb2,
    const float* W3, const float* pb3,
    float* effOut, float* outF, float* plausOut, float* impOut)
{
  __shared__ unsigned short xbs[64 * 256];   // 32 KB, XB stripe, live all kernel
  __shared__ unsigned short buf[64 * 256];   // 32 KB, stage-to-stage scratch
  __shared__ unsigned short Bs0[256 * 64];   // 32 KB, B-chunk buffer 0
  __shared__ unsigned short Bs1[256 * 64];   // 32 KB, B-chunk buffer 1
  __shared__ float impLds[64 * 4];
  int tid = threadIdx.x, w = tid >> 6, lane = tid & 63;
  int rowg = w >> 2, colg = w & 3;
  int rowBlk = blockIdx.x * 64;
  int rl0 = rowg * 32 + (lane & 15);
  int colBase = colg * 64;
  int c0 = colBase + (lane & 15);
  int kb = (lane >> 4) * 8;
  f32x4 acc[2][4];
  float effv[2][4][4];                 // deferred effOut values
  float finv[2][4][4];                 // deferred outF values

  // staging-unit dispatch (u is compile-time after unroll)
  auto stage_unit = [&](int u, unsigned short* Bs){
    if (u < 4)       stage256(Bt1, u*64, w, lane, Bs);
    else if (u < 8)  stage256(Bt2, (u-4)*64, w, lane, Bs);
    else if (u < 12) stage256(Mt, (u-8)*64, w, lane, Bs);
    else           { stage128(W1ab, (u-12)*64, w, lane, Bs);
                     stage128(W1c,  (u-12)*64, w, lane, Bs + 8192); }
  };
  // counted-vmcnt chunk prologue: bar0 -> issue(next) -> vmcnt(4) -> bar1
  auto chunk_sync = [&](int u, bool issueNext){
    __builtin_amdgcn_s_barrier();                    // bar0: prev chunk reads done
    if (issueNext) stage_unit(u + 1, (u & 1) ? Bs0 : Bs1);
    if (issueNext) asm volatile("s_waitcnt vmcnt(4)" ::: "memory");
    else           asm volatile("s_waitcnt vmcnt(0)" ::: "memory");
    __builtin_amdgcn_s_barrier();                    // bar1: chunk u in LDS
    __builtin_amdgcn_sched_barrier(0);
  };

  // ---- prologue: XB stripe + unit 0, one full drain
  stageA64(XB, rowBlk, w, lane, xbs);
  stage_unit(0, Bs0);
  __syncthreads();

  // ---- stage 1: H = relu(X@W1^T + b1) * |delta_k| -> buf
#pragma unroll
  for (int fm = 0; fm < 2; fm++)
#pragma unroll
    for (int fn = 0; fn < 4; fn++) acc[fm][fn] = (f32x4){0.f,0.f,0.f,0.f};
#pragma unroll
  for (int kc = 0; kc < 4; kc++){
    int u = kc;
    chunk_sync(u, true);
    __builtin_amdgcn_s_setprio(1);
    mm_lA<4>(xbs, (u & 1) ? Bs1 : Bs0, rl0, c0, kb, kc*64, acc);
    __builtin_amdgcn_s_setprio(0);
  }
  __syncthreads();                     // full drain before epilogue writes buf
  {
    float b1v[4];
#pragma unroll
    for (int fn = 0; fn < 4; fn++) b1v[fn] = eb1[colBase + fn*16 + (lane & 15)];
#pragma unroll
    for (int fm = 0; fm < 2; fm++)
#pragma unroll
      for (int i = 0; i < 4; i++){
        int rl = rowg*32 + fm*16 + (lane >> 4)*4 + i;
        int gr = rowBlk + rl;
        float mg = fabsf(delta[gr*4 + colg]);
        int sw = (rl & 7) << 3;
#pragma unroll
        for (int fn = 0; fn < 4; fn++){
          int col = colBase + fn*16 + (lane & 15);
          float h = acc[fm][fn][i] + b1v[fn];
          h = h > 0.f ? h : 0.f;
          buf[(size_t)rl*256 + (col ^ sw)] = f2b(h * mg);
        }
      }
  }
  __syncthreads();

  // ---- stage 2: eff = H@W2f + sum|d_k| b2[k] -> effv ; D = base+eff -> buf
#pragma unroll
  for (int fm = 0; fm < 2; fm++)
#pragma unroll
    for (int fn = 0; fn < 4; fn++) acc[fm][fn] = (f32x4){0.f,0.f,0.f,0.f};
#pragma unroll
  for (int kc = 0; kc < 4; kc++){
    int u = 4 + kc;
    chunk_sync(u, true);
    __builtin_amdgcn_s_setprio(1);
    mm_lA<4>(buf, (u & 1) ? Bs1 : Bs0, rl0, c0, kb, kc*64, acc);
    __builtin_amdgcn_s_setprio(0);
  }
  __syncthreads();
  {
    float bb0[4], bb1[4], bb2[4], bb3[4];
    int imv[4];
#pragma unroll
    for (int fn = 0; fn < 4; fn++){
      int col = colBase + fn*16 + (lane & 15);
      bb0[fn] = eb2[col]; bb1[fn] = eb2[256 + col];
      bb2[fn] = eb2[512 + col]; bb3[fn] = eb2[768 + col];
      imv[fn] = colmap[col];
    }
#pragma unroll
    for (int fm = 0; fm < 2; fm++)
#pragma unroll
      for (int i = 0; i < 4; i++){
        int rl = rowg*32 + fm*16 + (lane >> 4)*4 + i;
        int gr = rowBlk + rl;
        f32x4 dl = *(const f32x4*)&delta[gr*4];
        float d0a = fabsf(dl[0]), d1a = fabsf(dl[1]), d2a = fabsf(dl[2]), d3a = fabsf(dl[3]);
        int sw = (rl & 7) << 3;
#pragma unroll
        for (int fn = 0; fn < 4; fn++){
          int col = colBase + fn*16 + (lane & 15);
          float eff = acc[fm][fn][i] + d0a*bb0[fn] + d1a*bb1[fn] + d2a*bb2[fn] + d3a*bb3[fn];
          effv[fm][i][fn] = eff;                     // deferred
          float base = (imv[fn] >= 0) ? IV[gr*4 + imv[fn]]
                                      : b2f(xbs[(size_t)rl*256 + (col ^ sw)]);
          buf[(size_t)rl*256 + (col ^ sw)] = f2b(base + eff);
        }
      }
  }
  __syncthreads();

  // ---- stage 3: final = D@M -> finv ; Fin -> buf ; impact partials
#pragma unroll
  for (int fm = 0; fm < 2; fm++)
#pragma unroll
    for (int fn = 0; fn < 4; fn++) acc[fm][fn] = (f32x4){0.f,0.f,0.f,0.f};
#pragma unroll
  for (int kc = 0; kc < 4; kc++){
    int u = 8 + kc;
    chunk_sync(u, true);
    __builtin_amdgcn_s_setprio(1);
    mm_lA<4>(buf, (u & 1) ? Bs1 : Bs0, rl0, c0, kb, kc*64, acc);
    __builtin_amdgcn_s_setprio(0);
  }
  __syncthreads();
  {
#pragma unroll
    for (int fm = 0; fm < 2; fm++)
#pragma unroll
      for (int i = 0; i < 4; i++){
        int rl = rowg*32 + fm*16 + (lane >> 4)*4 + i;
        int sw = (rl & 7) << 3;
        float ss = 0.f;
#pragma unroll
        for (int fn = 0; fn < 4; fn++){
          int col = colBase + fn*16 + (lane & 15);
          float fv = acc[fm][fn][i];
          finv[fm][i][fn] = fv;                      // deferred
          buf[(size_t)rl*256 + (col ^ sw)] = f2b(fv);
          float d = fv - b2f(xbs[(size_t)rl*256 + (col ^ sw)]);
          ss += d * d;
        }
        ss += __shfl_xor(ss, 1, 64); ss += __shfl_xor(ss, 2, 64);
        ss += __shfl_xor(ss, 4, 64); ss += __shfl_xor(ss, 8, 64);
        if ((lane & 15) == 0) impLds[rl*4 + colg] = ss;
      }
  }
  __syncthreads();

  // ---- stage 4: P1 = relu(X@W1ab^T + Fin@W1c^T + delta corr + b1) -> buf
  {
    f32x4 a4[2][2];
#pragma unroll
    for (int fm = 0; fm < 2; fm++)
#pragma unroll
      for (int fn = 0; fn < 2; fn++) a4[fm][fn] = (f32x4){0.f,0.f,0.f,0.f};
    int c4 = colg * 32 + (lane & 15);
#pragma unroll
    for (int kc = 0; kc < 4; kc++){
      int u = 12 + kc;
      chunk_sync(u, kc < 3);
      const unsigned short* B = (u & 1) ? Bs1 : Bs0;
      __builtin_amdgcn_s_setprio(1);
      mm_lA<2>(xbs, B, rl0, c4, kb, kc*64, a4);          // X @ W1ab^T
      mm_lA<2>(buf, B + 8192, rl0, c4, kb, kc*64, a4);   // Fin @ W1c^T
      __builtin_amdgcn_s_setprio(0);
    }
    __syncthreads();
    float bv[2];
    f32x4 wb[2];
#pragma unroll
    for (int fn = 0; fn < 2; fn++){
      int col = colg*32 + fn*16 + (lane & 15);
      bv[fn] = pb1[col];
      wb[fn] = *(const f32x4*)&w1bcol[col*4];
    }
#pragma unroll
    for (int fm = 0; fm < 2; fm++)
#pragma unroll
      for (int i = 0; i < 4; i++){
        int rl = rowg*32 + fm*16 + (lane >> 4)*4 + i;
        int gr = rowBlk + rl;
        f32x4 dl = *(const f32x4*)&delta[gr*4];
        int sw = (rl & 7) << 3;
#pragma unroll
        for (int fn = 0; fn < 2; fn++){
          int col = colg*32 + fn*16 + (lane & 15);
          float p = a4[fm][fn][i] + bv[fn]
                  + dl[0]*wb[fn][0] + dl[1]*wb[fn][1] + dl[2]*wb[fn][2] + dl[3]*wb[fn][3];
          p = p > 0.f ? p : 0.f;
          buf[(size_t)rl*128 + (col ^ sw)] = f2b(p);
        }
      }
  }
  __syncthreads();

  // ---- deferred output stores (no barrier follows -> no vmcnt(0) drain)
#pragma unroll
  for (int fm = 0; fm < 2; fm++)
#pragma unroll
    for (int i = 0; i < 4; i++){
      int gr = rowBlk + rowg*32 + fm*16 + (lane >> 4)*4 + i;
#pragma unroll
      for (int fn = 0; fn < 4; fn++){
        size_t idx = (size_t)gr*VDIM + colBase + fn*16 + (lane & 15);
        effOut[idx] = effv[fm][i][fn];
        outF[idx]   = finv[fm][i][fn];
      }
    }

  // ---- stage 5: P2 = relu(P1@W2^T + b2); plaus; impact finish
  if (w < 4){
    int rl0b = w * 16 + (lane & 15);
    f32x4 a2[4];
#pragma unroll
    for (int fn = 0; fn < 4; fn++) a2[fn] = (f32x4){0.f,0.f,0.f,0.f};
    mm_l1<4, 128>(buf, 128, W2bf, 128, rl0b, (lane & 15), kb, a2);
    float b2v[4], w3v[4];
#pragma unroll
    for (int fn = 0; fn < 4; fn++){
      int col = fn*16 + (lane & 15);
      b2v[fn] = pb2[col]; w3v[fn] = W3[col];
    }
    float b3v = pb3[0];
#pragma unroll
    for (int i = 0; i < 4; i++){
      float s = 0.f;
#pragma unroll
      for (int fn = 0; fn < 4; fn++){
        float p2 = a2[fn][i] + b2v[fn];
        p2 = p2 > 0.f ? p2 : 0.f;
        s += p2 * w3v[fn];
      }
      s += __shfl_xor(s, 1, 64); s += __shfl_xor(s, 2, 64);
      s += __shfl_xor(s, 4, 64); s += __shfl_xor(s, 8, 64);
      if ((lane & 15) == 0){
        int gr = rowBlk + w*16 + (lane >> 4)*4 + i;
        plausOut[gr] = 1.f / (1.f + expf(-(s + b3v)));
      }
    }
  } else if (w == 4){
    f32x4 v = *(const f32x4*)&impLds[lane * 4];
    impOut[rowBlk + lane] = sqrtf(v[0] + v[1] + v[2] + v[3]);
  }
}

// ---- workspace layout (bytes) ----------------------------------------------
#define WS_XB     ((size_t)0)           // 16 MB
#define WS_DELTA  ((size_t)16777216)    // 512 KB
#define WS_SEG    ((size_t)17301504)    // 4 MB
#define WS_T2     ((size_t)21495808)    // 1 MB
#define WS_R      ((size_t)22544384)    // 256 KB
#define WS_MT     ((size_t)22806528)    // 128 KB
#define WS_BT1    ((size_t)22937600)    // 128 KB
#define WS_BT2    ((size_t)23068672)    // 128 KB
#define WS_W1AB   ((size_t)23199744)    // 64 KB
#define WS_W1C    ((size_t)23265280)    // 64 KB
#define WS_W2BF   ((size_t)23330816)    // 16 KB
#define WS_W1BCOL ((size_t)23347200)    // 2 KB
#define WS_COLMAP ((size_t)23349248)    // 1 KB

extern "C" void kernel_launch(void* const* d_in, const int* in_sizes, int n_in,
                              void* d_out, int out_size, void* d_ws, size_t ws_size,
                              hipStream_t stream)
{
  const float* X     = (const float*)d_in[0];
  const float* IV    = (const float*)d_in[1];
  const float* STR   = (const float*)d_in[2];
  const int*   IVARS = (const int*)d_in[3];
  const int*   CIDX  = (const int*)d_in[4];
  const int*   EIDX  = (const int*)d_in[5];
  const float* EW1   = (const float*)d_in[6];
  const float* EB1   = (const float*)d_in[7];
  const float* EW2   = (const float*)d_in[8];
  const float* EB2   = (const float*)d_in[9];
  const float* PW1   = (const float*)d_in[10];
  const float* PB1   = (const float*)d_in[11];
  const float* PW2   = (const float*)d_in[12];
  const float* PB2   = (const float*)d_in[13];
  const float* PW3   = (const float*)d_in[14];
  const float* PB3   = (const float*)d_in[15];

  char* ws = (char*)d_ws;
  unsigned short* XB     = (unsigned short*)(ws + WS_XB);
  float*          DELTA  = (float*)(ws + WS_DELTA);
  float*          SEG    = (float*)(ws + WS_SEG);
  float*          T2     = (float*)(ws + WS_T2);
  float*          Rm     = (float*)(ws + WS_R);
  unsigned short* MT     = (unsigned short*)(ws + WS_MT);
  unsigned short* BT1    = (unsigned short*)(ws + WS_BT1);
  unsigned short* BT2    = (unsigned short*)(ws + WS_BT2);
  unsigned short* W1AB   = (unsigned short*)(ws + WS_W1AB);
  unsigned short* W1C    = (unsigned short*)(ws + WS_W1C);
  unsigned short* W2BF   = (unsigned short*)(ws + WS_W2BF);
  float*          W1BCOL = (float*)(ws + WS_W1BCOL);
  int*            COLMAP = (int*)(ws + WS_COLMAP);

  float* outF   = (float*)d_out;                       // final_cf  [B,V]
  float* outEff = outF + (size_t)BDIM * VDIM;          // effects   [B,V]
  float* outPl  = outEff + (size_t)BDIM * VDIM;        // plaus     [B]
  float* outIm  = outPl + BDIM;                        // impact    [B]

  prep_seg<<<2048, 256, 0, stream>>>(X, IV, IVARS, EW1, EW2, PW1, PW2,
                                     CIDX, EIDX, STR,
                                     XB, BT1, BT2, W1AB, W1C, W2BF, W1BCOL, COLMAP,
                                     DELTA, SEG);
  combine4<<<256, 256, 0, stream>>>(SEG, T2);    // 16 segs -> 4
  combine4<<<64, 256, 0, stream>>>(T2, Rm);      // 4 -> R
  powM<<<64, 256, 0, stream>>>(Rm, MT);          // M = R^3, transposed bf16

  mega3<<<512, 512, 0, stream>>>(IV, XB, BT1, BT2, MT, W1AB, W1C, W2BF,
                                 EB1, EB2, DELTA, COLMAP, W1BCOL,
                                 PB1, PB2, PW3, PB3,
                                 outEff, outF, outPl, outIm);

  (void)in_sizes; (void)n_in; (void)out_size; (void)ws_size;
}

// Round 16
// 166.298 us; speedup vs baseline: 1.0219x; 1.0219x over previous
//
#include <hip/hip_runtime.h>

#define BDIM 32768
#define VDIM 256
#define KVAR 4
#define EDIM 2048
#define SEGS 16
#define SEGLEN 128   // EDIM / SEGS

typedef __attribute__((ext_vector_type(8))) short short8;
typedef __attribute__((ext_vector_type(4))) float f32x4;

__device__ __forceinline__ unsigned short f2b(float f){
  union { float f; unsigned u; } v; v.f = f;
  unsigned r = v.u + 0x7FFFu + ((v.u >> 16) & 1u);   // round-to-nearest-even
  return (unsigned short)(r >> 16);
}
__device__ __forceinline__ float b2f(unsigned short h){
  union { unsigned u; float f; } v; v.u = ((unsigned)h) << 16;
  return v.f;
}
__device__ __forceinline__ short8 ldb8(const unsigned short* p){
  return *(const short8*)p;
}

// async 16B global -> LDS (dest = wave-uniform base + lane*16)
__device__ __forceinline__ void gl_lds16(const unsigned short* g, unsigned short* l){
  __builtin_amdgcn_global_load_lds(
      (const __attribute__((address_space(1))) unsigned int*)g,
      (__attribute__((address_space(3))) unsigned int*)l, 16, 0, 0);
}

// ---- LDS staging (all source-swizzled: LDS 16B-slot s of row r holds global
// slot s ^ (r&7); reads XOR the same -> conflict-free) ----------------------
// B panel K-chunk: 256 rows x 64 k (32 KB). 8 waves x 4 issues x 1 KB.
__device__ __forceinline__ void stage256(const unsigned short* Bt, int kB,
                                         int w, int lane, unsigned short* Bs){
#pragma unroll
  for (int i = 0; i < 4; i++){
    int g8 = i*8 + w;                  // row-group of 8 (0..31)
    int r  = g8*8 + (lane >> 3);
    int s  = lane & 7;
    gl_lds16(Bt + (size_t)r*VDIM + kB + ((s ^ (r & 7)) << 3),
             Bs + (size_t)g8*512);
  }
}
// 128-row panel K-chunk (16 KB). 8 waves x 2 issues.
__device__ __forceinline__ void stage128(const unsigned short* Bt, int kB,
                                         int w, int lane, unsigned short* Bs){
#pragma unroll
  for (int i = 0; i < 2; i++){
    int g8 = i*8 + w;                  // 0..15
    int r  = g8*8 + (lane >> 3);       // 0..127
    int s  = lane & 7;
    gl_lds16(Bt + (size_t)r*VDIM + kB + ((s ^ (r & 7)) << 3),
             Bs + (size_t)g8*512);
  }
}
// XB stripe: 64 rows x 256 cols (32 KB), full-width swizzled rows
// (same element layout as buf: elem(r,c) at r*256 + (c ^ ((r&7)<<3))).
__device__ __forceinline__ void stageA64(const unsigned short* XBg, int rowBlk,
                                         int w, int lane, unsigned short* As){
#pragma unroll
  for (int i = 0; i < 4; i++){
    int pair = i*8 + w;                // 0..31, 2 rows per 1KB issue
    int r = pair*2 + (lane >> 5);      // 0..63
    int s = lane & 31;                 // 16B slot within 512B row
    gl_lds16(XBg + (size_t)(rowBlk + r)*VDIM + ((s ^ (r & 7)) << 3),
             As + (size_t)pair*512);
  }
}

// swizzled B-fragment read (klocal = k within 64-chunk, multiple of 8)
__device__ __forceinline__ short8 bs_frag(const unsigned short* Bs, int c, int klocal){
  int slot = klocal >> 3;
  return *(const short8*)&Bs[(size_t)c*64 + ((slot ^ (c & 7)) << 3)];
}

// ---- MFMA chunk core (one 64-wide K-chunk) ---------------------------------
// D frag: col = lane&15, row = (lane>>4)*4 + reg   [measured: learn_hip m89]
// A from swizzled 256-elem LDS rows (xbs or buf); B from swizzled Bs chunk.
template<int NF>
__device__ __forceinline__ void mm_lA(const unsigned short* Alds,
                                      const unsigned short* Bs,
                                      int rl0, int c0, int kb, int kB,
                                      f32x4 (&acc)[2][NF])
{
  int sw = (rl0 & 7) << 3;             // (rl0+16)&7 == rl0&7
#pragma unroll
  for (int k = 0; k < 2; k++){
    int ka = kB + k*32 + kb;
    short8 a0 = *(const short8*)&Alds[(size_t)rl0 * 256 + (ka ^ sw)];
    short8 a1 = *(const short8*)&Alds[(size_t)(rl0+16) * 256 + (ka ^ sw)];
#pragma unroll
    for (int fn = 0; fn < NF; fn++){
      short8 b = bs_frag(Bs, c0 + fn*16, k*32 + kb);
      acc[0][fn] = __builtin_amdgcn_mfma_f32_16x16x32_bf16(a0, b, acc[0][fn], 0, 0, 0);
      acc[1][fn] = __builtin_amdgcn_mfma_f32_16x16x32_bf16(a1, b, acc[1][fn], 0, 0, 0);
    }
  }
}
// single 16-row A frag from swizzled LDS (ldaE-elem rows), B per-lane global
// (tiny W2 panel, stage-5 only)
template<int NF, int KSZ>
__device__ __forceinline__ void mm_l1(const unsigned short* Alds, int ldaE,
                                      const unsigned short* Bt, int ldb,
                                      int rl0, int c0, int kb,
                                      f32x4 (&acc)[NF])
{
  int sw = (rl0 & 7) << 3;
#pragma unroll
  for (int k0 = 0; k0 < KSZ; k0 += 32){
    int ka = k0 + kb;
    short8 a0 = *(const short8*)&Alds[(size_t)rl0 * ldaE + (ka ^ sw)];
#pragma unroll
    for (int fn = 0; fn < NF; fn++){
      short8 b = ldb8(Bt + (size_t)(c0 + fn*16)*ldb + ka);
      acc[fn] = __builtin_amdgcn_mfma_f32_16x16x32_bf16(a0, b, acc[fn], 0, 0, 0);
    }
  }
}

// ---- merged prep + seg_build (block-partitioned) ---------------------------
__global__ __launch_bounds__(256) void prep_seg(
    const float* X, const float* IV, const int* ivars,
    const float* eW1, const float* eW2, const float* pW1, const float* pW2,
    const int* cidx, const int* eidx, const float* stren,
    unsigned short* XB,
    unsigned short* bt1, unsigned short* bt2,
    unsigned short* w1ab, unsigned short* w1c,
    unsigned short* w2bf, float* w1bcol, int* colmap,
    float* delta, float* segs)
{
  if (blockIdx.x < 1024){
    __shared__ int lc[SEGLEN];
    __shared__ int le[SEGLEN];
    __shared__ float la[SEGLEN];
    int bid = blockIdx.x;            // 64 per segment, 4 rows each
    int seg = bid >> 6;
    int rowbase = (bid & 63) * 4;
    int w = threadIdx.x >> 6, lane = threadIdx.x & 63;
    int row = rowbase + w;
    int k0 = seg * SEGLEN;
    for (int t = threadIdx.x; t < SEGLEN; t += 256){
      lc[t] = cidx[k0 + t]; le[t] = eidx[k0 + t]; la[t] = stren[k0 + t] * 0.1f;
    }
    __syncthreads();
    float r0 = (row == lane)        ? 1.f : 0.f;
    float r1 = (row == lane + 64)   ? 1.f : 0.f;
    float r2 = (row == lane + 128)  ? 1.f : 0.f;
    float r3 = (row == lane + 192)  ? 1.f : 0.f;
    for (int t = 0; t < SEGLEN; t++){
      int cs = __builtin_amdgcn_readfirstlane(lc[t]);
      int es = __builtin_amdgcn_readfirstlane(le[t]);
      float a = la[t];
      float vr;
      switch (cs >> 6){ case 0: vr = r0; break; case 1: vr = r1; break;
                        case 2: vr = r2; break; default: vr = r3; }
      float v = __shfl(vr, cs & 63, 64);
      float add = (lane == (es & 63)) ? a * v : 0.f;
      switch (es >> 6){ case 0: r0 += add; break; case 1: r1 += add; break;
                        case 2: r2 += add; break; default: r3 += add; }
    }
    float* out = segs + (size_t)seg * 65536 + (size_t)row * 256;
    out[lane] = r0; out[lane + 64] = r1; out[lane + 128] = r2; out[lane + 192] = r3;
    return;
  }
  int stride = 1024 * 256;
  int g0 = (blockIdx.x - 1024) * 256 + threadIdx.x;
  for (int i = g0; i < (BDIM * VDIM) / 8; i += stride){
    const float* p = X + (size_t)i * 8;
    f32x4 lo = *(const f32x4*)p;
    f32x4 hi = *(const f32x4*)(p + 4);
    short8 r;
    r[0]=(short)f2b(lo[0]); r[1]=(short)f2b(lo[1]); r[2]=(short)f2b(lo[2]); r[3]=(short)f2b(lo[3]);
    r[4]=(short)f2b(hi[0]); r[5]=(short)f2b(hi[1]); r[6]=(short)f2b(hi[2]); r[7]=(short)f2b(hi[3]);
    *(short8*)(XB + (size_t)i * 8) = r;
  }
  for (int i = g0; i < 65536; i += stride) bt1[i] = f2b(eW1[i]);
  for (int i = g0; i < 65536; i += stride){
    int v = i >> 8, r = i & 255;
    bt2[i] = f2b(eW2[(r >> 6) * 16384 + v * 64 + (r & 63)]);
  }
  for (int i = g0; i < 32768; i += stride){
    int o = i >> 8, v = i & 255;
    w1ab[i] = f2b(pW1[o*768 + v] + pW1[o*768 + 256 + v]);
    w1c[i]  = f2b(pW1[o*768 + 512 + v]);
  }
  for (int i = g0; i < 8192; i += stride) w2bf[i] = f2b(pW2[i]);
  for (int i = g0; i < 512; i += stride){
    int o = i >> 2, k = i & 3;
    w1bcol[i] = pW1[o*768 + 256 + ivars[k]];
  }
  for (int i = g0; i < VDIM; i += stride){
    int m = -1;
#pragma unroll
    for (int k = 0; k < KVAR; k++) if (ivars[k] == i) m = k;
    colmap[i] = m;
  }
  for (int i = g0; i < BDIM * KVAR; i += stride){
    int b = i >> 2, k = i & 3;
    delta[i] = IV[i] - X[(size_t)b * VDIM + ivars[k]];
  }
}

// ---- combine: Out[m] = S[4m]*S[4m+1]*S[4m+2]*S[4m+3], 4 rows per block -----
__global__ __launch_bounds__(256) void combine4(const float* S, float* Out)
{
  int m = blockIdx.x >> 6;
  int rb = (blockIdx.x & 63) * 4;
  int c = threadIdx.x;
  __shared__ float v[4][256];
  const float* base = S + (size_t)m * 4 * 65536;
#pragma unroll
  for (int r = 0; r < 4; r++) v[r][c] = base[(size_t)(rb + r) * 256 + c];
  __syncthreads();
  for (int p = 1; p < 4; p++){
    const float* Bm = base + (size_t)p * 65536;
    float a0 = 0.f, a1 = 0.f, a2 = 0.f, a3 = 0.f;
    for (int k = 0; k < 256; k += 4){
      f32x4 v0 = *(const f32x4*)&v[0][k];
      f32x4 v1 = *(const f32x4*)&v[1][k];
      f32x4 v2 = *(const f32x4*)&v[2][k];
      f32x4 v3 = *(const f32x4*)&v[3][k];
#pragma unroll
      for (int j = 0; j < 4; j++){
        float bk = Bm[(size_t)(k + j) * 256 + c];
        a0 += v0[j] * bk; a1 += v1[j] * bk; a2 += v2[j] * bk; a3 += v3[j] * bk;
      }
    }
    __syncthreads();
    v[0][c] = a0; v[1][c] = a1; v[2][c] = a2; v[3][c] = a3;
    __syncthreads();
  }
#pragma unroll
  for (int r = 0; r < 4; r++) Out[(size_t)m * 65536 + (size_t)(rb + r) * 256 + c] = v[r][c];
}

// ---- M = R*R*R, written transposed bf16: Mt[c][r] --------------------------
__global__ __launch_bounds__(256) void powM(const float* R, unsigned short* Mt)
{
  int rb = blockIdx.x * 4;
  int c = threadIdx.x;
  __shared__ float v[4][256];
#pragma unroll
  for (int r = 0; r < 4; r++) v[r][c] = R[(size_t)(rb + r) * 256 + c];
  __syncthreads();
  for (int p = 0; p < 2; p++){
    float a0 = 0.f, a1 = 0.f, a2 = 0.f, a3 = 0.f;
    for (int k = 0; k < 256; k += 4){
      f32x4 v0 = *(const f32x4*)&v[0][k];
      f32x4 v1 = *(const f32x4*)&v[1][k];
      f32x4 v2 = *(const f32x4*)&v[2][k];
      f32x4 v3 = *(const f32x4*)&v[3][k];
#pragma unroll
      for (int j = 0; j < 4; j++){
        float bk = R[(size_t)(k + j) * 256 + c];
        a0 += v0[j] * bk; a1 += v1[j] * bk; a2 += v2[j] * bk; a3 += v3[j] * bk;
      }
    }
    __syncthreads();
    v[0][c] = a0; v[1][c] = a1; v[2][c] = a2; v[3][c] = a3;
    __syncthreads();
  }
#pragma unroll
  for (int r = 0; r < 4; r++) Mt[(size_t)c * 256 + (rb + r)] = f2b(v[r][c]);
}

// ============================================================================
// MEGA3D (session best, r14-measured 83.7us / 166.36us total): fused 5-stage
// pipeline, 64-row stripe, 512 thr (8 waves = 2 rowg x 4 colg), wave tile
// 32x64.  16 B-panel staging units double-buffered in Bs[2], issued one
// ahead; XB stripe DMA'd once; deferred output stores (no barrier after ->
// no vmcnt(0) drain).  LDS 129 KB -> 1 block/CU.
// Plateau note (r15): occupancy, counted-vmcnt, nt-stores, scratch re-fusion
// and wave-count variants all measured null or negative; residual idle cycles
// are distributed across epilogue VALU, scalar ds_writes, and 22 lockstep
// barrier skews -- no single removable >10us term identified.
// ============================================================================
__global__ __launch_bounds__(512) void mega3(
    const float* IV, const unsigned short* XB,
    const unsigned short* Bt1, const unsigned short* Bt2, const unsigned short* Mt,
    const unsigned short* W1ab, const unsigned short* W1c, const unsigned short* W2bf,
    const float* eb1, const float* eb2, const float* delta, const int* colmap,
    const float* w1bcol, const float* pb1, const float* pb2,
    const float* W3, const float* pb3,
    float* effOut, float* outF, float* plausOut, float* impOut)
{
  __shared__ unsigned short xbs[64 * 256];   // 32 KB, XB stripe, live all kernel
  __shared__ unsigned short buf[64 * 256];   // 32 KB, stage-to-stage scratch
  __shared__ unsigned short Bs0[256 * 64];   // 32 KB, B-chunk buffer 0
  __shared__ unsigned short Bs1[256 * 64];   // 32 KB, B-chunk buffer 1
  __shared__ float impLds[64 * 4];
  int tid = threadIdx.x, w = tid >> 6, lane = tid & 63;
  int rowg = w >> 2, colg = w & 3;
  int rowBlk = blockIdx.x * 64;
  int rl0 = rowg * 32 + (lane & 15);
  int colBase = colg * 64;
  int c0 = colBase + (lane & 15);
  int kb = (lane >> 4) * 8;
  f32x4 acc[2][4];
  float effv[2][4][4];                 // deferred effOut values
  float finv[2][4][4];                 // deferred outF values

  // staging-unit dispatch (u is compile-time after unroll)
  auto stage_unit = [&](int u, unsigned short* Bs){
    if (u < 4)       stage256(Bt1, u*64, w, lane, Bs);
    else if (u < 8)  stage256(Bt2, (u-4)*64, w, lane, Bs);
    else if (u < 12) stage256(Mt, (u-8)*64, w, lane, Bs);
    else           { stage128(W1ab, (u-12)*64, w, lane, Bs);
                     stage128(W1c,  (u-12)*64, w, lane, Bs + 8192); }
  };

  // ---- prologue: XB stripe + unit 0, one drain
  stageA64(XB, rowBlk, w, lane, xbs);
  stage_unit(0, Bs0);
  __syncthreads();

  // ---- stage 1: H = relu(X@W1^T + b1) * |delta_k| -> buf
#pragma unroll
  for (int fm = 0; fm < 2; fm++)
#pragma unroll
    for (int fn = 0; fn < 4; fn++) acc[fm][fn] = (f32x4){0.f,0.f,0.f,0.f};
#pragma unroll
  for (int kc = 0; kc < 4; kc++){
    int u = kc;
    stage_unit(u + 1, (u & 1) ? Bs0 : Bs1);          // prefetch next unit
    __builtin_amdgcn_s_setprio(1);
    mm_lA<4>(xbs, (u & 1) ? Bs1 : Bs0, rl0, c0, kb, kc*64, acc);
    __builtin_amdgcn_s_setprio(0);
    __syncthreads();                                  // drains prefetch too
  }
  {
    float b1v[4];
#pragma unroll
    for (int fn = 0; fn < 4; fn++) b1v[fn] = eb1[colBase + fn*16 + (lane & 15)];
#pragma unroll
    for (int fm = 0; fm < 2; fm++)
#pragma unroll
      for (int i = 0; i < 4; i++){
        int rl = rowg*32 + fm*16 + (lane >> 4)*4 + i;
        int gr = rowBlk + rl;
        float mg = fabsf(delta[gr*4 + colg]);
        int sw = (rl & 7) << 3;
#pragma unroll
        for (int fn = 0; fn < 4; fn++){
          int col = colBase + fn*16 + (lane & 15);
          float h = acc[fm][fn][i] + b1v[fn];
          h = h > 0.f ? h : 0.f;
          buf[(size_t)rl*256 + (col ^ sw)] = f2b(h * mg);
        }
      }
  }
  __syncthreads();

  // ---- stage 2: eff = H@W2f + sum|d_k| b2[k] -> effv ; D = base+eff -> buf
#pragma unroll
  for (int fm = 0; fm < 2; fm++)
#pragma unroll
    for (int fn = 0; fn < 4; fn++) acc[fm][fn] = (f32x4){0.f,0.f,0.f,0.f};
#pragma unroll
  for (int kc = 0; kc < 4; kc++){
    int u = 4 + kc;
    stage_unit(u + 1, (u & 1) ? Bs0 : Bs1);
    __builtin_amdgcn_s_setprio(1);
    mm_lA<4>(buf, (u & 1) ? Bs1 : Bs0, rl0, c0, kb, kc*64, acc);
    __builtin_amdgcn_s_setprio(0);
    __syncthreads();
  }
  {
    float bb0[4], bb1[4], bb2[4], bb3[4];
    int imv[4];
#pragma unroll
    for (int fn = 0; fn < 4; fn++){
      int col = colBase + fn*16 + (lane & 15);
      bb0[fn] = eb2[col]; bb1[fn] = eb2[256 + col];
      bb2[fn] = eb2[512 + col]; bb3[fn] = eb2[768 + col];
      imv[fn] = colmap[col];
    }
#pragma unroll
    for (int fm = 0; fm < 2; fm++)
#pragma unroll
      for (int i = 0; i < 4; i++){
        int rl = rowg*32 + fm*16 + (lane >> 4)*4 + i;
        int gr = rowBlk + rl;
        f32x4 dl = *(const f32x4*)&delta[gr*4];
        float d0a = fabsf(dl[0]), d1a = fabsf(dl[1]), d2a = fabsf(dl[2]), d3a = fabsf(dl[3]);
        int sw = (rl & 7) << 3;
#pragma unroll
        for (int fn = 0; fn < 4; fn++){
          int col = colBase + fn*16 + (lane & 15);
          float eff = acc[fm][fn][i] + d0a*bb0[fn] + d1a*bb1[fn] + d2a*bb2[fn] + d3a*bb3[fn];
          effv[fm][i][fn] = eff;                     // DEFERRED (was global store)
          float base = (imv[fn] >= 0) ? IV[gr*4 + imv[fn]]
                                      : b2f(xbs[(size_t)rl*256 + (col ^ sw)]);
          buf[(size_t)rl*256 + (col ^ sw)] = f2b(base + eff);
        }
      }
  }
  __syncthreads();

  // ---- stage 3: final = D@M -> finv ; Fin -> buf ; impact partials
#pragma unroll
  for (int fm = 0; fm < 2; fm++)
#pragma unroll
    for (int fn = 0; fn < 4; fn++) acc[fm][fn] = (f32x4){0.f,0.f,0.f,0.f};
#pragma unroll
  for (int kc = 0; kc < 4; kc++){
    int u = 8 + kc;
    stage_unit(u + 1, (u & 1) ? Bs0 : Bs1);
    __builtin_amdgcn_s_setprio(1);
    mm_lA<4>(buf, (u & 1) ? Bs1 : Bs0, rl0, c0, kb, kc*64, acc);
    __builtin_amdgcn_s_setprio(0);
    __syncthreads();
  }
  {
#pragma unroll
    for (int fm = 0; fm < 2; fm++)
#pragma unroll
      for (int i = 0; i < 4; i++){
        int rl = rowg*32 + fm*16 + (lane >> 4)*4 + i;
        int sw = (rl & 7) << 3;
        float ss = 0.f;
#pragma unroll
        for (int fn = 0; fn < 4; fn++){
          int col = colBase + fn*16 + (lane & 15);
          float fv = acc[fm][fn][i];
          finv[fm][i][fn] = fv;                      // DEFERRED (was global store)
          buf[(size_t)rl*256 + (col ^ sw)] = f2b(fv);
          float d = fv - b2f(xbs[(size_t)rl*256 + (col ^ sw)]);
          ss += d * d;
        }
        ss += __shfl_xor(ss, 1, 64); ss += __shfl_xor(ss, 2, 64);
        ss += __shfl_xor(ss, 4, 64); ss += __shfl_xor(ss, 8, 64);
        if ((lane & 15) == 0) impLds[rl*4 + colg] = ss;
      }
  }
  __syncthreads();

  // ---- stage 4: P1 = relu(X@W1ab^T + Fin@W1c^T + delta corr + b1) -> buf
  {
    f32x4 a4[2][2];
#pragma unroll
    for (int fm = 0; fm < 2; fm++)
#pragma unroll
      for (int fn = 0; fn < 2; fn++) a4[fm][fn] = (f32x4){0.f,0.f,0.f,0.f};
    int c4 = colg * 32 + (lane & 15);
#pragma unroll
    for (int kc = 0; kc < 4; kc++){
      int u = 12 + kc;
      if (kc < 3) stage_unit(u + 1, (u & 1) ? Bs0 : Bs1);
      const unsigned short* B = (u & 1) ? Bs1 : Bs0;
      __builtin_amdgcn_s_setprio(1);
      mm_lA<2>(xbs, B, rl0, c4, kb, kc*64, a4);          // X @ W1ab^T
      mm_lA<2>(buf, B + 8192, rl0, c4, kb, kc*64, a4);   // Fin @ W1c^T
      __builtin_amdgcn_s_setprio(0);
      __syncthreads();
    }
    float bv[2];
    f32x4 wb[2];
#pragma unroll
    for (int fn = 0; fn < 2; fn++){
      int col = colg*32 + fn*16 + (lane & 15);
      bv[fn] = pb1[col];
      wb[fn] = *(const f32x4*)&w1bcol[col*4];
    }
#pragma unroll
    for (int fm = 0; fm < 2; fm++)
#pragma unroll
      for (int i = 0; i < 4; i++){
        int rl = rowg*32 + fm*16 + (lane >> 4)*4 + i;
        int gr = rowBlk + rl;
        f32x4 dl = *(const f32x4*)&delta[gr*4];
        int sw = (rl & 7) << 3;
#pragma unroll
        for (int fn = 0; fn < 2; fn++){
          int col = colg*32 + fn*16 + (lane & 15);
          float p = a4[fm][fn][i] + bv[fn]
                  + dl[0]*wb[fn][0] + dl[1]*wb[fn][1] + dl[2]*wb[fn][2] + dl[3]*wb[fn][3];
          p = p > 0.f ? p : 0.f;
          buf[(size_t)rl*128 + (col ^ sw)] = f2b(p);
        }
      }
  }
  __syncthreads();

  // ---- deferred output stores (no barrier follows -> no vmcnt(0) drain;
  //      they stream out under the P2 compute and the kernel tail)
#pragma unroll
  for (int fm = 0; fm < 2; fm++)
#pragma unroll
    for (int i = 0; i < 4; i++){
      int gr = rowBlk + rowg*32 + fm*16 + (lane >> 4)*4 + i;
#pragma unroll
      for (int fn = 0; fn < 4; fn++){
        size_t idx = (size_t)gr*VDIM + colBase + fn*16 + (lane & 15);
        effOut[idx] = effv[fm][i][fn];
        outF[idx]   = finv[fm][i][fn];
      }
    }

  // ---- stage 5: P2 = relu(P1@W2^T + b2); plaus; impact finish
  if (w < 4){
    int rl0b = w * 16 + (lane & 15);
    f32x4 a2[4];
#pragma unroll
    for (int fn = 0; fn < 4; fn++) a2[fn] = (f32x4){0.f,0.f,0.f,0.f};
    mm_l1<4, 128>(buf, 128, W2bf, 128, rl0b, (lane & 15), kb, a2);
    float b2v[4], w3v[4];
#pragma unroll
    for (int fn = 0; fn < 4; fn++){
      int col = fn*16 + (lane & 15);
      b2v[fn] = pb2[col]; w3v[fn] = W3[col];
    }
    float b3v = pb3[0];
#pragma unroll
    for (int i = 0; i < 4; i++){
      float s = 0.f;
#pragma unroll
      for (int fn = 0; fn < 4; fn++){
        float p2 = a2[fn][i] + b2v[fn];
        p2 = p2 > 0.f ? p2 : 0.f;
        s += p2 * w3v[fn];
      }
      s += __shfl_xor(s, 1, 64); s += __shfl_xor(s, 2, 64);
      s += __shfl_xor(s, 4, 64); s += __shfl_xor(s, 8, 64);
      if ((lane & 15) == 0){
        int gr = rowBlk + w*16 + (lane >> 4)*4 + i;
        plausOut[gr] = 1.f / (1.f + expf(-(s + b3v)));
      }
    }
  } else if (w == 4){
    f32x4 v = *(const f32x4*)&impLds[lane * 4];
    impOut[rowBlk + lane] = sqrtf(v[0] + v[1] + v[2] + v[3]);
  }
}

// ---- workspace layout (bytes) ----------------------------------------------
#define WS_XB     ((size_t)0)           // 16 MB
#define WS_DELTA  ((size_t)16777216)    // 512 KB
#define WS_SEG    ((size_t)17301504)    // 4 MB
#define WS_T2     ((size_t)21495808)    // 1 MB
#define WS_R      ((size_t)22544384)    // 256 KB
#define WS_MT     ((size_t)22806528)    // 128 KB
#define WS_BT1    ((size_t)22937600)    // 128 KB
#define WS_BT2    ((size_t)23068672)    // 128 KB
#define WS_W1AB   ((size_t)23199744)    // 64 KB
#define WS_W1C    ((size_t)23265280)    // 64 KB
#define WS_W2BF   ((size_t)23330816)    // 16 KB
#define WS_W1BCOL ((size_t)23347200)    // 2 KB
#define WS_COLMAP ((size_t)23349248)    // 1 KB

extern "C" void kernel_launch(void* const* d_in, const int* in_sizes, int n_in,
                              void* d_out, int out_size, void* d_ws, size_t ws_size,
                              hipStream_t stream)
{
  const float* X     = (const float*)d_in[0];
  const float* IV    = (const float*)d_in[1];
  const float* STR   = (const float*)d_in[2];
  const int*   IVARS = (const int*)d_in[3];
  const int*   CIDX  = (const int*)d_in[4];
  const int*   EIDX  = (const int*)d_in[5];
  const float* EW1   = (const float*)d_in[6];
  const float* EB1   = (const float*)d_in[7];
  const float* EW2   = (const float*)d_in[8];
  const float* EB2   = (const float*)d_in[9];
  const float* PW1   = (const float*)d_in[10];
  const float* PB1   = (const float*)d_in[11];
  const float* PW2   = (const float*)d_in[12];
  const float* PB2   = (const float*)d_in[13];
  const float* PW3   = (const float*)d_in[14];
  const float* PB3   = (const float*)d_in[15];

  char* ws = (char*)d_ws;
  unsigned short* XB     = (unsigned short*)(ws + WS_XB);
  float*          DELTA  = (float*)(ws + WS_DELTA);
  float*          SEG    = (float*)(ws + WS_SEG);
  float*          T2     = (float*)(ws + WS_T2);
  float*          Rm     = (float*)(ws + WS_R);
  unsigned short* MT     = (unsigned short*)(ws + WS_MT);
  unsigned short* BT1    = (unsigned short*)(ws + WS_BT1);
  unsigned short* BT2    = (unsigned short*)(ws + WS_BT2);
  unsigned short* W1AB   = (unsigned short*)(ws + WS_W1AB);
  unsigned short* W1C    = (unsigned short*)(ws + WS_W1C);
  unsigned short* W2BF   = (unsigned short*)(ws + WS_W2BF);
  float*          W1BCOL = (float*)(ws + WS_W1BCOL);
  int*            COLMAP = (int*)(ws + WS_COLMAP);

  float* outF   = (float*)d_out;                       // final_cf  [B,V]
  float* outEff = outF + (size_t)BDIM * VDIM;          // effects   [B,V]
  float* outPl  = outEff + (size_t)BDIM * VDIM;        // plaus     [B]
  float* outIm  = outPl + BDIM;                        // impact    [B]

  prep_seg<<<2048, 256, 0, stream>>>(X, IV, IVARS, EW1, EW2, PW1, PW2,
                                     CIDX, EIDX, STR,
                                     XB, BT1, BT2, W1AB, W1C, W2BF, W1BCOL, COLMAP,
                                     DELTA, SEG);
  combine4<<<256, 256, 0, stream>>>(SEG, T2);    // 16 segs -> 4
  combine4<<<64, 256, 0, stream>>>(T2, Rm);      // 4 -> R
  powM<<<64, 256, 0, stream>>>(Rm, MT);          // M = R^3, transposed bf16

  mega3<<<512, 512, 0, stream>>>(IV, XB, BT1, BT2, MT, W1AB, W1C, W2BF,
                                 EB1, EB2, DELTA, COLMAP, W1BCOL,
                                 PB1, PB2, PW3, PB3,
                                 outEff, outF, outPl, outIm);

  (void)in_sizes; (void)n_in; (void)out_size; (void)ws_size;
}